// Round 1
// baseline (453.428 us; speedup 1.0000x reference)
//
#include <hip/hip_runtime.h>
#include <cstddef>

#define TEMP_MIN_F 1e-4f

constexpr int kS = 1024;   // frames
constexpr int kB = 256;    // batch
constexpr int kN = 256;    // channels
constexpr int kM = 512;    // z rows
constexpr int kE = 64;     // experts
constexpr int kT = kS - 1; // valid attention steps

__device__ __forceinline__ float waveReduceSum(float v) {
#pragma unroll
  for (int off = 32; off >= 1; off >>= 1) v += __shfl_xor(v, off, 64);
  return v;
}
__device__ __forceinline__ float waveReduceMin(float v) {
#pragma unroll
  for (int off = 32; off >= 1; off >>= 1) v = fminf(v, __shfl_xor(v, off, 64));
  return v;
}
__device__ __forceinline__ float waveReduceMax(float v) {
#pragma unroll
  for (int off = 32; off >= 1; off >>= 1) v = fmaxf(v, __shfl_xor(v, off, 64));
  return v;
}

// One block per batch element b. 512 threads = 8 waves.
// Pass A: distances d[t] = sum_i |ctx[t,b,i] - z[i,b]|  (t < 1023)
// softmax over t in LDS.
// Pass B: c0[i] = sum_t attn[t]*ctx[t,b,i]; c1[i] = sum_t attn[t]*ctx[t+1,b,i]
// Then: embedding[o] = sum_i conv_w[o,i,0]*c0[i] + conv_w[o,i,1]*c1[i] + conv_b[o]
//       h[e] = relu(sum_j combined[j]*W1[e,j]);  mlp[e2] = sum_e h[e]*W2[e2,e]
//       out[e2,b] = softmax_e2(-mlp/temp2)
__global__ __launch_bounds__(512)
void gating_fused(const float* __restrict__ context,
                  const float* __restrict__ z,
                  const float* __restrict__ conv_w,
                  const float* __restrict__ conv_b,
                  const float* __restrict__ W1,
                  const float* __restrict__ W2,
                  const float* __restrict__ t1p,
                  const float* __restrict__ t2p,
                  float* __restrict__ out) {
  const int b    = blockIdx.x;
  const int tid  = threadIdx.x;
  const int wave = tid >> 6;
  const int lane = tid & 63;

  __shared__ __align__(16) float s_w[kT + 1];       // distances -> unnorm weights
  __shared__ __align__(16) float s_z[kM];           // z[:, b]
  __shared__ __align__(16) float s_c[2][kN];        // reduced c0, c1
  __shared__ __align__(16) float s_part[8][2 * kN]; // per-wave partials (16 KB)
  __shared__ __align__(16) float s_emb[kN];
  __shared__ float s_h[kE];
  __shared__ float s_red[16];

  // stage z column b (strided reads; z is small + cache-resident)
  for (int m = tid; m < kM; m += 512) s_z[m] = z[(size_t)m * kB + b];
  __syncthreads();

  const float temp1  = fmaxf(fabsf(t1p[0]), TEMP_MIN_F);
  const float inv_t1 = 1.0f / temp1;

  const float4 zz = ((const float4*)s_z)[lane]; // z_cur[b, 4l..4l+3]

  // ---- Pass A: L1 distances ----
  for (int t = wave; t < kT; t += 8) {
    float4 x = *(const float4*)(context + ((size_t)t * kB + b) * kN + 4 * lane);
    float d = fabsf(x.x - zz.x) + fabsf(x.y - zz.y) +
              fabsf(x.z - zz.z) + fabsf(x.w - zz.w);
    d = waveReduceSum(d);
    if (lane == 0) s_w[t] = d;
  }
  __syncthreads();

  // ---- softmax over t: weight_t = exp((dmin - d_t)/temp1), normalize by l ----
  float mloc = 1e30f;
  for (int t = tid; t < kT; t += 512) mloc = fminf(mloc, s_w[t]);
  mloc = waveReduceMin(mloc);
  if (lane == 0) s_red[wave] = mloc;
  __syncthreads();
  if (tid == 0) {
    float mm = s_red[0];
#pragma unroll
    for (int w = 1; w < 8; ++w) mm = fminf(mm, s_red[w]);
    s_red[8] = mm;
  }
  __syncthreads();
  const float dmin = s_red[8];

  float lsum = 0.f;
  for (int t = tid; t < kT; t += 512) {
    float e = expf((dmin - s_w[t]) * inv_t1);
    s_w[t] = e;          // own slot: no cross-thread hazard
    lsum += e;
  }
  lsum = waveReduceSum(lsum);
  if (lane == 0) s_red[wave] = lsum;
  __syncthreads();
  if (tid == 0) {
    float tot = 0.f;
#pragma unroll
    for (int w = 0; w < 8; ++w) tot += s_red[w];
    s_red[9] = 1.0f / tot;
  }
  __syncthreads();
  const float inv_l = s_red[9];

  // ---- Pass B: weighted sums c0, c1 (single pass over all S rows) ----
  float c00 = 0.f, c01 = 0.f, c02 = 0.f, c03 = 0.f;
  float c10 = 0.f, c11 = 0.f, c12 = 0.f, c13 = 0.f;
  for (int t = wave; t < kS; t += 8) {
    float4 x = *(const float4*)(context + ((size_t)t * kB + b) * kN + 4 * lane);
    float w0 = (t < kT) ? s_w[t] : 0.f;      // weight for c0 (uses row t)
    float w1 = (t > 0) ? s_w[t - 1] : 0.f;   // weight for c1 (row t = frame t-1 shifted)
    c00 += w0 * x.x; c01 += w0 * x.y; c02 += w0 * x.z; c03 += w0 * x.w;
    c10 += w1 * x.x; c11 += w1 * x.y; c12 += w1 * x.z; c13 += w1 * x.w;
  }
  ((float4*)&s_part[wave][0])[lane] =
      make_float4(c00 * inv_l, c01 * inv_l, c02 * inv_l, c03 * inv_l);
  ((float4*)&s_part[wave][kN])[lane] =
      make_float4(c10 * inv_l, c11 * inv_l, c12 * inv_l, c13 * inv_l);
  __syncthreads();
  if (tid < kN) {
    float a0 = 0.f, a1 = 0.f;
#pragma unroll
    for (int w = 0; w < 8; ++w) {
      a0 += s_part[w][tid];
      a1 += s_part[w][kN + tid];
    }
    s_c[0][tid] = a0;
    s_c[1][tid] = a1;
  }
  __syncthreads();

  // ---- embedding[o] = conv_w[o,:,0].c0 + conv_w[o,:,1].c1 + conv_b[o] ----
  const float4 cc0 = ((const float4*)&s_c[0][0])[lane];
  const float4 cc1 = ((const float4*)&s_c[1][0])[lane];
  for (int o = wave; o < kN; o += 8) {
    const float4* wrow = (const float4*)(conv_w + (size_t)o * (2 * kN));
    float4 wa = wrow[2 * lane];       // (i=4l,k=0),(4l,1),(4l+1,0),(4l+1,1)
    float4 wb = wrow[2 * lane + 1];   // (4l+2,0),(4l+2,1),(4l+3,0),(4l+3,1)
    float acc = wa.x * cc0.x + wa.y * cc1.x + wa.z * cc0.y + wa.w * cc1.y +
                wb.x * cc0.z + wb.y * cc1.z + wb.z * cc0.w + wb.w * cc1.w;
    acc = waveReduceSum(acc);
    if (lane == 0) s_emb[o] = acc + conv_b[o];
  }
  __syncthreads();

  // ---- h[e] = relu(combined . W1[e,:]) ; combined = [embedding(256); z(512)] ----
  for (int e = wave; e < kE; e += 8) {
    const float* wr = W1 + (size_t)e * (kN + kM);
    float acc = 0.f;
#pragma unroll
    for (int jj = 0; jj < 12; ++jj) {
      int j = lane + 64 * jj;
      float cj = (j < kN) ? s_emb[j] : s_z[j - kN];
      acc += wr[j] * cj;
    }
    acc = waveReduceSum(acc);
    if (lane == 0) s_h[e] = fmaxf(acc, 0.f);
  }
  __syncthreads();

  // ---- mlp + softmax over E (wave 0, lane = e2) ----
  if (wave == 0) {
    const float temp2 = fmaxf(fabsf(t2p[0]), TEMP_MIN_F);
    float acc = 0.f;
    const float* w2r = W2 + (size_t)lane * kE;
#pragma unroll
    for (int e = 0; e < kE; ++e) acc += w2r[e] * s_h[e];
    float logit = -acc / temp2;
    float mx = waveReduceMax(logit);
    float ex = expf(logit - mx);
    float ssum = waveReduceSum(ex);
    out[(size_t)lane * kB + b] = ex / ssum;
  }
}

extern "C" void kernel_launch(void* const* d_in, const int* in_sizes, int n_in,
                              void* d_out, int out_size, void* d_ws, size_t ws_size,
                              hipStream_t stream) {
  const float* context = (const float*)d_in[0];
  const float* z       = (const float*)d_in[1];
  // d_in[2] = D — structurally [I_N | 0]; D@z == z[:N,:], so unused.
  const float* conv_w  = (const float*)d_in[3];
  const float* conv_b  = (const float*)d_in[4];
  const float* W1      = (const float*)d_in[5];
  const float* W2      = (const float*)d_in[6];
  const float* t1      = (const float*)d_in[7];
  const float* t2      = (const float*)d_in[8];
  float* out = (float*)d_out;

  hipLaunchKernelGGL(gating_fused, dim3(kB), dim3(512), 0, stream,
                     context, z, conv_w, conv_b, W1, W2, t1, t2, out);
}